// Round 4
// baseline (62771.063 us; speedup 1.0000x reference)
//
#include <hip/hip_runtime.h>
#include <cmath>

#define Bsz 128
#define Ssz 512
#define Isz 512
#define Hsz 1024
#define G4  4096
#define Ktot 1536

typedef short s8v __attribute__((ext_vector_type(8)));
typedef unsigned short u16x8 __attribute__((ext_vector_type(8)));
typedef float f32x16 __attribute__((ext_vector_type(16)));

__device__ __forceinline__ unsigned short f2bf(float f) {
    unsigned u = __float_as_uint(f);
    u += 0x7fffu + ((u >> 16) & 1u);
    return (unsigned short)(u >> 16);
}
__device__ __forceinline__ float bf2f(unsigned short h) {
    return __uint_as_float(((unsigned)h) << 16);
}
__device__ __forceinline__ float fsig(float v) { return 1.f / (1.f + __expf(-v)); }
__device__ __forceinline__ float ftanh(float v) { return 2.f / (1.f + __expf(-2.f * v)) - 1.f; }

__device__ __forceinline__ unsigned ld_acq(const unsigned* p) {
    return __hip_atomic_load(p, __ATOMIC_ACQUIRE, __HIP_MEMORY_SCOPE_AGENT);
}
// bounded spin: returns true on success, false on timeout (safety valve vs hang)
__device__ __forceinline__ bool wait_ge(const unsigned* p, unsigned tgt) {
    for (int i = 0; i < (1 << 19); ++i) {
        if (ld_acq(p) >= tgt) return true;
        __builtin_amdgcn_s_sleep(2);
    }
    return false;
}

// ---- build Ut[n][k]: transposed, gate-strided column permutation, bf16 hi/lo ----
// n = nb*64 + c ; c in [0,64): gate = c>>4, r = c&15 ; global col = gate*1024 + nb*16 + r
__global__ __launch_bounds__(256) void conv_ut(const float* __restrict__ W,
                                               const float* __restrict__ U,
                                               unsigned short* __restrict__ Uthi,
                                               unsigned short* __restrict__ Utlo) {
    __shared__ float tile[32][33];
    const int n0 = blockIdx.x * 32, k0 = blockIdx.y * 32;
    const int tx = threadIdx.x & 31, ty = threadIdx.x >> 5;
    const int nb = n0 >> 6;
    const int c = (n0 & 63) + tx;
    const int col = ((c >> 4) << 10) + (nb << 4) + (c & 15);
    #pragma unroll
    for (int rr = 0; rr < 4; ++rr) {
        int k = k0 + ty + rr * 8;
        float v = (k < Isz) ? W[(size_t)k * G4 + col] : U[(size_t)(k - Isz) * G4 + col];
        tile[ty + rr * 8][tx] = v;
    }
    __syncthreads();
    #pragma unroll
    for (int rr = 0; rr < 4; ++rr) {
        int nl = ty + rr * 8;
        float v = tile[tx][nl];
        unsigned short h = f2bf(v);
        size_t dst = (size_t)(n0 + nl) * Ktot + k0 + tx;
        Uthi[dst] = h;
        Utlo[dst] = f2bf(v - bf2f(h));
    }
}

__global__ __launch_bounds__(256) void zero_ws(unsigned int* __restrict__ p, int n) {
    int i = blockIdx.x * 256 + threadIdx.x;
    if (i < n) p[i] = 0;
}

// ---- persistent LSTM: grid 256 = nb(64) x kt(4), 1 block/CU, plain launch ----
// block 256 thr = 4 waves: (mh, kk) = (w&1, w>>1); wave tile M64 x N64 x K192.
// B frags persistent in VGPRs. ctr: [0,64) ctrP, [64,128) ctrC, [128,132) ctrH, [132] ctrG
__global__ __launch_bounds__(256, 1) void lstm_persist(
    const float* __restrict__ x,
    const unsigned short* __restrict__ Uthi,
    const unsigned short* __restrict__ Utlo,
    const float* __restrict__ bias,
    float* __restrict__ P,              // [2][3][64][8192]
    unsigned short* __restrict__ hpl,   // [3][2][128*1024]
    unsigned int* __restrict__ ctr,
    float* __restrict__ out)
{
    __shared__ float gacc[128 * 64];
    __shared__ unsigned short hst[2][128 * 16];
    __shared__ float sbias[64];

    const int tid  = threadIdx.x;
    const int lane = tid & 63, w = tid >> 6;
    const int nb = blockIdx.x & 63, kt = blockIdx.x >> 6;
    const int mh = w & 1;
    const int kk = w >> 1;
    const int l31 = lane & 31;
    const int koff = (lane >> 5) << 3;

    if (tid < 64) sbias[tid] = bias[((tid >> 4) << 10) + (nb << 4) + (tid & 15)];

    unsigned int* ctrP = ctr;
    unsigned int* ctrC = ctr + 64;
    unsigned int* ctrH = ctr + 128;
    unsigned int* ctrG = ctr + 132;

    // persistent B fragments: 12 K16-steps x 2 n-chunks, hi+lo (192 VGPRs)
    const int ksbase = kt * 384 + kk * 192;
    s8v Bh[12][2], Bl[12][2];
    #pragma unroll
    for (int ks = 0; ks < 12; ++ks) {
        #pragma unroll
        for (int ni = 0; ni < 2; ++ni) {
            size_t off = (size_t)((nb << 6) + (ni << 5) + l31) * Ktot + ksbase + ks * 16 + koff;
            Bh[ks][ni] = *(const s8v*)(Uthi + off);
            Bl[ks][ni] = *(const s8v*)(Utlo + off);
        }
    }

    const int b0 = (mh << 6) + l31;
    const size_t xrow0 = (size_t)b0 * (Ssz * Isz);
    const size_t xrow1 = (size_t)(b0 + 32) * (Ssz * Isz);

    float c_reg[8], hs_reg[8];
    #pragma unroll
    for (int u = 0; u < 8; ++u) { c_reg[u] = 0.f; hs_reg[u] = 0.f; }

    bool dead = false;   // meaningful in tid0 only
    int pin = 2;         // h-input plane = (t+2)%3

    #pragma unroll 1
    for (int t = 0; t < Ssz; ++t) {
        // ---- wait for the h(t-1) quarters this K-slice reads ----
        if (kt) {
            if (tid == 0 && !dead) {
                unsigned tgt = 16u * (unsigned)t;
                if (kt == 1) {
                    dead |= !wait_ge(&ctrH[0], tgt);
                } else if (kt == 2) {
                    dead |= !wait_ge(&ctrH[1], tgt);
                    dead |= !wait_ge(&ctrH[2], tgt);
                } else {
                    dead |= !wait_ge(&ctrH[2], tgt);
                    dead |= !wait_ge(&ctrH[3], tgt);
                }
            }
            __syncthreads();
            // per-thread acquire on the gating counters (L1/L2 invalidate)
            if (kt == 1)      { (void)ld_acq(&ctrH[0]); }
            else if (kt == 2) { (void)ld_acq(&ctrH[1]); (void)ld_acq(&ctrH[2]); }
            else              { (void)ld_acq(&ctrH[2]); (void)ld_acq(&ctrH[3]); }
        }
        const unsigned short* hhi_in = hpl + (size_t)pin * (2 * Bsz * Hsz);
        const unsigned short* hlo_in = hhi_in + Bsz * Hsz;

        f32x16 A00, A01, A10, A11;
        #pragma unroll
        for (int i = 0; i < 16; ++i) { A00[i] = 0.f; A01[i] = 0.f; A10[i] = 0.f; A11[i] = 0.f; }

        // ---- K-loop: 12 x K16 ----
        #pragma unroll
        for (int ks = 0; ks < 12; ++ks) {
            const int gkb = ksbase + ks * 16;
            s8v ah0, al0, ah1, al1;
            if (gkb < Isz) {
                const float* xp0 = x + xrow0 + (size_t)t * Isz + gkb + koff;
                const float* xp1 = x + xrow1 + (size_t)t * Isz + gkb + koff;
                float4 v0 = *(const float4*)xp0;
                float4 v1 = *(const float4*)(xp0 + 4);
                float4 v2 = *(const float4*)xp1;
                float4 v3 = *(const float4*)(xp1 + 4);
                float f0[8] = {v0.x, v0.y, v0.z, v0.w, v1.x, v1.y, v1.z, v1.w};
                float f1[8] = {v2.x, v2.y, v2.z, v2.w, v3.x, v3.y, v3.z, v3.w};
                #pragma unroll
                for (int j = 0; j < 8; ++j) {
                    unsigned short h0 = f2bf(f0[j]);
                    ah0[j] = (short)h0; al0[j] = (short)f2bf(f0[j] - bf2f(h0));
                    unsigned short h1 = f2bf(f1[j]);
                    ah1[j] = (short)h1; al1[j] = (short)f2bf(f1[j] - bf2f(h1));
                }
            } else {
                size_t o0 = (size_t)b0 * Hsz + (gkb - Isz) + koff;
                size_t o1 = (size_t)(b0 + 32) * Hsz + (gkb - Isz) + koff;
                ah0 = *(const s8v*)(hhi_in + o0);
                al0 = *(const s8v*)(hlo_in + o0);
                ah1 = *(const s8v*)(hhi_in + o1);
                al1 = *(const s8v*)(hlo_in + o1);
            }
            A00 = __builtin_amdgcn_mfma_f32_32x32x16_bf16(ah0, Bh[ks][0], A00, 0, 0, 0);
            A01 = __builtin_amdgcn_mfma_f32_32x32x16_bf16(ah0, Bh[ks][1], A01, 0, 0, 0);
            A10 = __builtin_amdgcn_mfma_f32_32x32x16_bf16(ah1, Bh[ks][0], A10, 0, 0, 0);
            A11 = __builtin_amdgcn_mfma_f32_32x32x16_bf16(ah1, Bh[ks][1], A11, 0, 0, 0);
            A00 = __builtin_amdgcn_mfma_f32_32x32x16_bf16(al0, Bh[ks][0], A00, 0, 0, 0);
            A01 = __builtin_amdgcn_mfma_f32_32x32x16_bf16(al0, Bh[ks][1], A01, 0, 0, 0);
            A10 = __builtin_amdgcn_mfma_f32_32x32x16_bf16(al1, Bh[ks][0], A10, 0, 0, 0);
            A11 = __builtin_amdgcn_mfma_f32_32x32x16_bf16(al1, Bh[ks][1], A11, 0, 0, 0);
            A00 = __builtin_amdgcn_mfma_f32_32x32x16_bf16(ah0, Bl[ks][0], A00, 0, 0, 0);
            A01 = __builtin_amdgcn_mfma_f32_32x32x16_bf16(ah0, Bl[ks][1], A01, 0, 0, 0);
            A10 = __builtin_amdgcn_mfma_f32_32x32x16_bf16(ah1, Bl[ks][0], A10, 0, 0, 0);
            A11 = __builtin_amdgcn_mfma_f32_32x32x16_bf16(ah1, Bl[ks][1], A11, 0, 0, 0);
        }

        // ---- in-block k2 reduce into gacc ----
        const int rbase = (lane >> 5) << 2;
        if (kk == 1) {
            #pragma unroll
            for (int r = 0; r < 16; ++r) {
                int row = (r & 3) + ((r >> 2) << 3) + rbase;
                int g0 = ((mh << 6) + row) * 64;
                gacc[g0 + l31]                  = A00[r];
                gacc[g0 + 32 + l31]             = A01[r];
                gacc[g0 + (32 << 6) + l31]      = A10[r];
                gacc[g0 + (32 << 6) + 32 + l31] = A11[r];
            }
        }
        __syncthreads();
        if (kk == 0) {
            #pragma unroll
            for (int r = 0; r < 16; ++r) {
                int row = (r & 3) + ((r >> 2) << 3) + rbase;
                int g0 = ((mh << 6) + row) * 64;
                gacc[g0 + l31]                  += A00[r];
                gacc[g0 + 32 + l31]             += A01[r];
                gacc[g0 + (32 << 6) + l31]      += A10[r];
                gacc[g0 + (32 << 6) + 32 + l31] += A11[r];
            }
        }
        __syncthreads();
        // publish grid progress: this block finished GEMM (all h reads) of step t
        if (tid == 0)
            __hip_atomic_fetch_add(ctrG, 1u, __ATOMIC_RELEASE, __HIP_MEMORY_SCOPE_AGENT);

        float* Pslot = P + (size_t)(t & 1) * (3 * 64 * 8192);
        if (kt < 3) {
            // ---- worker: dump partial, gated on consumption of slot (t-2) ----
            if (tid == 0 && t >= 2 && !dead)
                dead |= !wait_ge(&ctrC[nb], (unsigned)(t - 1));
            __syncthreads();
            float* dst = Pslot + ((size_t)kt * 64 + nb) * 8192;
            #pragma unroll
            for (int i = 0; i < 8; ++i) {
                int idx = (i * 256 + tid) * 4;
                *(float4*)(dst + idx) = *(const float4*)(gacc + idx);
            }
            __syncthreads();
            if (tid == 0)
                __hip_atomic_fetch_add(&ctrP[nb], 1u, __ATOMIC_RELEASE, __HIP_MEMORY_SCOPE_AGENT);
        } else {
            // ---- finisher: collect partials, pointwise, write h ----
            if (tid == 0 && !dead)
                dead |= !wait_ge(&ctrP[nb], 3u * (unsigned)(t + 1));
            __syncthreads();
            (void)ld_acq(&ctrP[nb]);   // per-thread acquire
            #pragma unroll
            for (int k = 0; k < 3; ++k) {
                const float* src = Pslot + ((size_t)k * 64 + nb) * 8192;
                #pragma unroll
                for (int i = 0; i < 8; ++i) {
                    int idx = (i * 256 + tid) * 4;
                    float4 v = *(const float4*)(src + idx);
                    gacc[idx + 0] += v.x; gacc[idx + 1] += v.y;
                    gacc[idx + 2] += v.z; gacc[idx + 3] += v.w;
                }
            }
            __syncthreads();
            if (tid == 0)
                __hip_atomic_fetch_add(&ctrC[nb], 1u, __ATOMIC_RELEASE, __HIP_MEMORY_SCOPE_AGENT);

            const int pout = (pin + 1 == 3) ? 0 : pin + 1;  // t % 3
            unsigned short* hhi_o = hpl + (size_t)pout * (2 * Bsz * Hsz);
            unsigned short* hlo_o = hhi_o + Bsz * Hsz;
            #pragma unroll
            for (int u = 0; u < 8; ++u) {
                int id = tid * 8 + u;
                int b = id >> 4, r = id & 15;
                float gf = gacc[b * 64 + r]      + sbias[r];
                float gi = gacc[b * 64 + 16 + r] + sbias[16 + r];
                float gg = gacc[b * 64 + 32 + r] + sbias[32 + r];
                float go = gacc[b * 64 + 48 + r] + sbias[48 + r];
                float f  = fsig(gf);
                float i_ = fsig(gi);
                float g  = ftanh(gg);
                float o  = fsig(go);
                float cn = f * c_reg[u] + i_ * g;
                c_reg[u] = cn;
                float hn = o * ftanh(cn);
                hs_reg[u] += hn;
                unsigned short hh = f2bf(hn);
                hst[0][b * 16 + r] = hh;
                hst[1][b * 16 + r] = f2bf(hn - bf2f(hh));
            }
            // anti-overwrite gate: plane (t%3) was read during GEMMs of step t-2;
            // wait until every block has finished GEMM of step t-2 (count >= 256*(t-1))
            if (tid == 0 && t >= 2 && !dead)
                dead |= !wait_ge(ctrG, 256u * (unsigned)(t - 1));
            __syncthreads();
            {
                int pl = tid >> 7, row = tid & 127;
                const unsigned short* s = &hst[pl][row * 16];
                unsigned short* d = (pl ? hlo_o : hhi_o) + (size_t)row * Hsz + (nb << 4);
                *(u16x8*)d       = *(const u16x8*)s;
                *(u16x8*)(d + 8) = *(const u16x8*)(s + 8);
            }
            __syncthreads();
            if (tid == 0)
                __hip_atomic_fetch_add(&ctrH[nb >> 4], 1u, __ATOMIC_RELEASE, __HIP_MEMORY_SCOPE_AGENT);
        }
        pin = (pin + 1 == 3) ? 0 : pin + 1;
    }

    if (kt == 3) {
        #pragma unroll
        for (int u = 0; u < 8; ++u) {
            int id = tid * 8 + u;
            int b = id >> 4, r = id & 15;
            out[(size_t)b * Hsz + (nb << 4) + r] = hs_reg[u] * (1.f / (float)Ssz);
        }
    }
}

extern "C" void kernel_launch(void* const* d_in, const int* in_sizes, int n_in,
                              void* d_out, int out_size, void* d_ws, size_t ws_size,
                              hipStream_t stream) {
    const float* x    = (const float*)d_in[0];
    const float* W    = (const float*)d_in[1];
    const float* U    = (const float*)d_in[2];
    const float* bias = (const float*)d_in[3];
    float* out = (float*)d_out;

    unsigned char* base = (unsigned char*)d_ws;
    unsigned short* Uthi = (unsigned short*)(base);                     // 12,582,912
    unsigned short* Utlo = (unsigned short*)(base + 12582912);          // 12,582,912
    float*          P    = (float*)(base + 25165824);                   // 12,582,912
    unsigned short* hpl  = (unsigned short*)(base + 37748736);          //  1,572,864
    unsigned int*   ctr  = (unsigned int*)(base + 39321600);            //       576

    conv_ut<<<dim3(G4 / 32, Ktot / 32), 256, 0, stream>>>(W, U, Uthi, Utlo);

    // zero h planes (3*2*128*1024 u16 = 393216 u32) + 144 counter words (contiguous)
    {
        int nz = 393216 + 144;
        zero_ws<<<(nz + 255) / 256, 256, 0, stream>>>((unsigned int*)hpl, nz);
    }

    lstm_persist<<<dim3(256), dim3(256), 0, stream>>>(
        x, Uthi, Utlo, bias, P, hpl, ctr, out);
}

// Round 5
// 22371.404 us; speedup vs baseline: 2.8059x; 2.8059x over previous
//
#include <hip/hip_runtime.h>
#include <cmath>

#define Bsz 128
#define Ssz 512
#define Isz 512
#define Hsz 1024
#define G4  4096
#define Ktot 1536

typedef short s8v __attribute__((ext_vector_type(8)));
typedef unsigned short u16x8 __attribute__((ext_vector_type(8)));
typedef float f32x16 __attribute__((ext_vector_type(16)));

__device__ __forceinline__ unsigned short f2bf(float f) {
    unsigned u = __float_as_uint(f);
    u += 0x7fffu + ((u >> 16) & 1u);
    return (unsigned short)(u >> 16);
}
__device__ __forceinline__ float bf2f(unsigned short h) {
    return __uint_as_float(((unsigned)h) << 16);
}
__device__ __forceinline__ float fsig(float v) { return 1.f / (1.f + __expf(-v)); }
__device__ __forceinline__ float ftanh(float v) { return 2.f / (1.f + __expf(-2.f * v)) - 1.f; }

// RELAXED poll — no cache maintenance per iteration
__device__ __forceinline__ bool wait_ge_rlx(const unsigned* p, unsigned tgt) {
    for (int i = 0; i < (1 << 17); ++i) {
        if (__hip_atomic_load(p, __ATOMIC_RELAXED, __HIP_MEMORY_SCOPE_AGENT) >= tgt)
            return true;
        __builtin_amdgcn_s_sleep(4);
    }
    return false;
}

// ---- build Ut[n][k]: transposed, gate-strided column permutation, bf16 hi/lo ----
// n = nb*64 + c ; c in [0,64): gate = c>>4, r = c&15 ; global col = gate*1024 + nb*16 + r
__global__ __launch_bounds__(256) void conv_ut(const float* __restrict__ W,
                                               const float* __restrict__ U,
                                               unsigned short* __restrict__ Uthi,
                                               unsigned short* __restrict__ Utlo) {
    __shared__ float tile[32][33];
    const int n0 = blockIdx.x * 32, k0 = blockIdx.y * 32;
    const int tx = threadIdx.x & 31, ty = threadIdx.x >> 5;
    const int nb = n0 >> 6;
    const int c = (n0 & 63) + tx;
    const int col = ((c >> 4) << 10) + (nb << 4) + (c & 15);
    #pragma unroll
    for (int rr = 0; rr < 4; ++rr) {
        int k = k0 + ty + rr * 8;
        float v = (k < Isz) ? W[(size_t)k * G4 + col] : U[(size_t)(k - Isz) * G4 + col];
        tile[ty + rr * 8][tx] = v;
    }
    __syncthreads();
    #pragma unroll
    for (int rr = 0; rr < 4; ++rr) {
        int nl = ty + rr * 8;
        float v = tile[tx][nl];
        unsigned short h = f2bf(v);
        size_t dst = (size_t)(n0 + nl) * Ktot + k0 + tx;
        Uthi[dst] = h;
        Utlo[dst] = f2bf(v - bf2f(h));
    }
}

__global__ __launch_bounds__(256) void zero_ws(unsigned int* __restrict__ p, int n) {
    int i = blockIdx.x * 256 + threadIdx.x;
    if (i < n) p[i] = 0;
}

// ---- persistent LSTM: grid 128 = nb(64) x mh(2), block 512 thr = 8 waves ----
// wave (nh = w>>2, kq = w&3): tile M64 x N32 x K384, FULL K within block -> no
// cross-block reduce. One cumulative counter; one acquire-inv + one release-wb
// per block per step. Weight hi-plane persistent in VGPRs; c,hsum in registers.
__global__ __launch_bounds__(512, 1) void lstm_persist(
    const float* __restrict__ x,
    const unsigned short* __restrict__ Uthi,
    const unsigned short* __restrict__ Utlo,
    const float* __restrict__ bias,
    unsigned short* __restrict__ hpl,   // [2 parity][2 plane][128*1024]
    unsigned int* __restrict__ ctr,
    float* __restrict__ out)
{
    __shared__ float G0[64 * 64];       // k-partials kq0+kq1  (K 0..767)
    __shared__ float G1[64 * 64];       // k-partials kq2+kq3  (K 768..1535)
    __shared__ unsigned short hst[2][64 * 16];
    __shared__ float sbias[64];

    const int tid  = threadIdx.x;
    const int lane = tid & 63, w = tid >> 6;
    const int nb = blockIdx.x & 63, mh = blockIdx.x >> 6;
    const int kq = w & 3, nh = w >> 2;
    const int l31 = lane & 31;
    const int koct = (lane >> 5) << 3;

    if (tid < 64) sbias[tid] = bias[((tid >> 4) << 10) + (nb << 4) + (tid & 15)];

    // ---- persistent B hi-plane: 24 K16-steps (96 VGPRs) ----
    const int colg = (nb << 6) + (nh << 5) + l31;   // Ut row (column of gates)
    const int kqb  = kq * 384;
    const size_t cbase = (size_t)colg * Ktot;
    s8v Bh[24];
    #pragma unroll
    for (int ks = 0; ks < 24; ++ks)
        Bh[ks] = *(const s8v*)(Uthi + cbase + kqb + ks * 16 + koct);

    const int b0 = (mh << 6) + l31;     // m-tile0 batch row (tile1 = +32)
    const size_t xr0 = (size_t)b0 * (Ssz * Isz);
    const size_t xr1 = (size_t)(b0 + 32) * (Ssz * Isz);

    float c_reg[2], hs_reg[2];
    c_reg[0] = c_reg[1] = hs_reg[0] = hs_reg[1] = 0.f;

    bool dead = false;   // tid0 only

    #pragma unroll 1
    for (int t = 0; t < Ssz; ++t) {
        // ---- single cross-block gate: all blocks published h(t-1) ----
        if (t > 0) {
            if (tid == 0) {
                if (!dead) dead |= !wait_ge_rlx(ctr, 128u * (unsigned)t);
                // exactly ONE acquire (buffer_inv) per block per step
                (void)__hip_atomic_load(ctr, __ATOMIC_ACQUIRE, __HIP_MEMORY_SCOPE_AGENT);
            }
            __syncthreads();
        }
        const unsigned short* hhi_in = hpl + (size_t)((t + 1) & 1) * (2 * Bsz * Hsz);
        const unsigned short* hlo_in = hhi_in + Bsz * Hsz;

        f32x16 A0, A1;
        #pragma unroll
        for (int i = 0; i < 16; ++i) { A0[i] = 0.f; A1[i] = 0.f; }

        // ---- K-loop: 24 x K16 (this wave's K384 slice) ----
        #pragma unroll
        for (int ks = 0; ks < 24; ++ks) {
            const int gk = kqb + ks * 16;
            s8v bl = *(const s8v*)(Utlo + cbase + gk + koct);
            s8v ah0, al0, ah1, al1;
            if (gk < Isz) {
                const float* xp0 = x + xr0 + (size_t)t * Isz + gk + koct;
                const float* xp1 = x + xr1 + (size_t)t * Isz + gk + koct;
                float4 v0 = *(const float4*)xp0;
                float4 v1 = *(const float4*)(xp0 + 4);
                float4 v2 = *(const float4*)xp1;
                float4 v3 = *(const float4*)(xp1 + 4);
                float f0[8] = {v0.x, v0.y, v0.z, v0.w, v1.x, v1.y, v1.z, v1.w};
                float f1[8] = {v2.x, v2.y, v2.z, v2.w, v3.x, v3.y, v3.z, v3.w};
                #pragma unroll
                for (int j = 0; j < 8; ++j) {
                    unsigned short h0 = f2bf(f0[j]);
                    ah0[j] = (short)h0; al0[j] = (short)f2bf(f0[j] - bf2f(h0));
                    unsigned short h1 = f2bf(f1[j]);
                    ah1[j] = (short)h1; al1[j] = (short)f2bf(f1[j] - bf2f(h1));
                }
            } else {
                size_t o0 = (size_t)b0 * Hsz + (gk - Isz) + koct;
                size_t o1 = (size_t)(b0 + 32) * Hsz + (gk - Isz) + koct;
                ah0 = *(const s8v*)(hhi_in + o0);
                al0 = *(const s8v*)(hlo_in + o0);
                ah1 = *(const s8v*)(hhi_in + o1);
                al1 = *(const s8v*)(hlo_in + o1);
            }
            A0 = __builtin_amdgcn_mfma_f32_32x32x16_bf16(ah0, Bh[ks], A0, 0, 0, 0);
            A1 = __builtin_amdgcn_mfma_f32_32x32x16_bf16(ah1, Bh[ks], A1, 0, 0, 0);
            A0 = __builtin_amdgcn_mfma_f32_32x32x16_bf16(al0, Bh[ks], A0, 0, 0, 0);
            A1 = __builtin_amdgcn_mfma_f32_32x32x16_bf16(al1, Bh[ks], A1, 0, 0, 0);
            A0 = __builtin_amdgcn_mfma_f32_32x32x16_bf16(ah0, bl, A0, 0, 0, 0);
            A1 = __builtin_amdgcn_mfma_f32_32x32x16_bf16(ah1, bl, A1, 0, 0, 0);
        }

        // ---- in-block k-reduce (4 partials -> G0,G1) ----
        // C/D: row = (r&3) + 8*(r>>2) + 4*(lane>>5), col = l31
        const int rbase = (lane >> 5) << 2;
        const int gcol  = (nh << 5) + l31;
        float* Gx = (kq < 2) ? G0 : G1;
        if (kq & 1) {
            #pragma unroll
            for (int r = 0; r < 16; ++r) {
                int row = (r & 3) + ((r >> 2) << 3) + rbase;
                Gx[row * 64 + gcol]        = A0[r];
                Gx[(row + 32) * 64 + gcol] = A1[r];
            }
        }
        __syncthreads();
        if (!(kq & 1)) {
            #pragma unroll
            for (int r = 0; r < 16; ++r) {
                int row = (r & 3) + ((r >> 2) << 3) + rbase;
                Gx[row * 64 + gcol]        += A0[r];
                Gx[(row + 32) * 64 + gcol] += A1[r];
            }
        }
        __syncthreads();

        // ---- pointwise: 1024 (b,r) pairs, 2 per thread; c,hsum in regs ----
        #pragma unroll
        for (int u = 0; u < 2; ++u) {
            int id = tid * 2 + u;
            int b = id >> 4, r = id & 15;
            float gf = G0[b * 64 + r]      + G1[b * 64 + r]      + sbias[r];
            float gi = G0[b * 64 + 16 + r] + G1[b * 64 + 16 + r] + sbias[16 + r];
            float gg = G0[b * 64 + 32 + r] + G1[b * 64 + 32 + r] + sbias[32 + r];
            float go = G0[b * 64 + 48 + r] + G1[b * 64 + 48 + r] + sbias[48 + r];
            float f  = fsig(gf);
            float i_ = fsig(gi);
            float g  = ftanh(gg);
            float o  = fsig(go);
            float cn = f * c_reg[u] + i_ * g;
            c_reg[u] = cn;
            float hn = o * ftanh(cn);
            hs_reg[u] += hn;
            unsigned short hh = f2bf(hn);
            hst[0][b * 16 + r] = hh;
            hst[1][b * 16 + r] = f2bf(hn - bf2f(hh));
        }
        __syncthreads();

        // ---- publish h(t) slice (rows mh*64.., cols nb*16..) ----
        unsigned short* ho = hpl + (size_t)(t & 1) * (2 * Bsz * Hsz);
        if (tid < 256) {
            int pl = tid >> 7, idx = tid & 127;
            int row = idx >> 1, oct = idx & 1;
            unsigned short* d = ho + (size_t)pl * (Bsz * Hsz)
                              + (size_t)((mh << 6) + row) * Hsz + (nb << 4) + oct * 8;
            *(u16x8*)d = *(const u16x8*)&hst[pl][row * 16 + oct * 8];
        }
        __syncthreads();   // drains stores (vmcnt) before the release
        if (tid == 0)
            __hip_atomic_fetch_add(ctr, 1u, __ATOMIC_RELEASE, __HIP_MEMORY_SCOPE_AGENT);
    }

    // ---- final output: disjoint (mh rows x nb cols) tiles ----
    #pragma unroll
    for (int u = 0; u < 2; ++u) {
        int id = tid * 2 + u;
        int b = (mh << 6) + (id >> 4), j = (nb << 4) + (id & 15);
        out[(size_t)b * Hsz + j] = hs_reg[u] * (1.f / (float)Ssz);
    }
}

extern "C" void kernel_launch(void* const* d_in, const int* in_sizes, int n_in,
                              void* d_out, int out_size, void* d_ws, size_t ws_size,
                              hipStream_t stream) {
    const float* x    = (const float*)d_in[0];
    const float* W    = (const float*)d_in[1];
    const float* U    = (const float*)d_in[2];
    const float* bias = (const float*)d_in[3];
    float* out = (float*)d_out;

    unsigned char* base = (unsigned char*)d_ws;
    unsigned short* Uthi = (unsigned short*)(base);                 // 12,582,912 B
    unsigned short* Utlo = (unsigned short*)(base + 12582912);      // 12,582,912 B
    unsigned short* hpl  = (unsigned short*)(base + 25165824);      //  1,048,576 B
    unsigned int*   ctr  = (unsigned int*)(base + 26214400);        //         64 B

    conv_ut<<<dim3(G4 / 32, Ktot / 32), 256, 0, stream>>>(W, U, Uthi, Utlo);

    // zero h planes (1,048,576 B = 262144 u32) + 16 counter words (contiguous)
    zero_ws<<<(262144 + 16 + 255) / 256, 256, 0, stream>>>((unsigned int*)hpl, 262144 + 16);

    lstm_persist<<<dim3(128), dim3(512), 0, stream>>>(
        x, Uthi, Utlo, bias, hpl, ctr, out);
}